// Round 1
// baseline (691.365 us; speedup 1.0000x reference)
//
#include <hip/hip_runtime.h>

// KAN conv feature extractor, fully fused: one workgroup per batch element.
// Layers: kanconv3x3(1->5) + maxpool2 -> kanconv5x5(5->5) -> kanconv3x3(5->2) -> FC(98->200)
// Each KAN conv = plain conv over "transformed" input channels:
//   per input pixel v: [silu(v), B0(v)..B7(v)]  (9 channels per input channel)
// Patch feature ordering (jax conv_general_dilated_patches): F = c*k*k + di*k + dj

__device__ __forceinline__ float silu_f(float v) {
    return v / (1.0f + __expf(-v));
}

// Cox-de Boor cubic B-spline basis, uniform knots grid[j] = (j-3)*0.4 - 1, j=0..11.
// Produces the 8 = G+K basis values, matching the reference recursion exactly
// (order-0 via >= / < on the same fp32 knot constants).
__device__ __forceinline__ void bspline8(float x, float* out) {
    const float h = 0.4f;
    float b[11];
#pragma unroll
    for (int j = 0; j < 11; ++j) {
        float gj  = (j - 3) * h - 1.0f;
        float gj1 = (j - 2) * h - 1.0f;
        b[j] = (x >= gj && x < gj1) ? 1.0f : 0.0f;
    }
#pragma unroll
    for (int p = 1; p <= 3; ++p) {
        float inv = 1.0f / (p * h);
#pragma unroll
        for (int j = 0; j + p < 11; ++j) {
            float gj   = (j - 3) * h - 1.0f;       // grid[j]
            float gjp1 = (j + p - 2) * h - 1.0f;   // grid[j+p+1]
            b[j] = (x - gj) * inv * b[j] + (gjp1 - x) * inv * b[j + 1];
        }
    }
#pragma unroll
    for (int j = 0; j < 8; ++j) out[j] = b[j];
}

// LDS layout (floats), overlaid phases:
//  t1: [0, 7056)      784 pixels x 9 ch       (phase 1-2)
//  h1: [7840, 8685)   [5][13*13]              (phase 2-3)
//  t2: [0, 7605)      169 pos x 45 ch         (phase 3-4)  (overwrites t1)
//  h2: [7605, 8010)   [5][9*9]                (phase 4-5)
//  t3: [0, 3645)      81 pos x 45 ch          (phase 5-6)  (overwrites t2)
//  h3: [3645, 3743)   [98]                    (phase 6-7)
#define SMEM_FLOATS 8704

__global__ __launch_bounds__(256) void kan_fused(
    const float* __restrict__ x,     // [B,1,28,28]
    const float* __restrict__ wb1,   // [5,9]
    const float* __restrict__ ws1,   // [5,9,8]
    const float* __restrict__ wb2,   // [5,125]
    const float* __restrict__ ws2,   // [5,125,8]
    const float* __restrict__ wb3,   // [2,45]
    const float* __restrict__ ws3,   // [2,45,8]
    const float* __restrict__ fcw,   // [200,98]
    const float* __restrict__ fcb,   // [200]
    float* __restrict__ out)         // [B,200]
{
    __shared__ float smem[SMEM_FLOATS];
    float* t1 = smem;          // [pixel][9]
    float* h1 = smem + 7840;   // [c*169 + pos]
    float* t2 = smem;          // [pos][45], ch = c*9 + m
    float* h2 = smem + 7605;   // [o*81 + pos]
    float* t3 = smem;          // [pos][45]
    float* h3 = smem + 3645;   // [98]

    const int b   = blockIdx.x;
    const int tid = threadIdx.x;

    // ---- Phase 1: transform input pixels -> t1 -------------------------
    for (int i = tid; i < 784; i += 256) {
        float v = x[b * 784 + i];
        float* t = t1 + i * 9;
        float bs[8];
        bspline8(v, bs);
        t[0] = silu_f(v);
#pragma unroll
        for (int g = 0; g < 8; ++g) t[1 + g] = bs[g];
    }
    __syncthreads();

    // ---- Phase 2: conv1 3x3 (9 tch -> 5) + maxpool2 -> h1 [5,13,13] ----
    for (int oidx = tid; oidx < 845; oidx += 256) {
        int c  = oidx / 169;
        int pp = oidx % 169;
        int ph = pp / 13, pw = pp % 13;
        float m = -INFINITY;
#pragma unroll
        for (int dy = 0; dy < 2; ++dy) {
#pragma unroll
            for (int dx = 0; dx < 2; ++dx) {
                int y  = 2 * ph + dy;
                int xx = 2 * pw + dx;
                float acc = 0.0f;
                for (int di = 0; di < 3; ++di) {
                    for (int dj = 0; dj < 3; ++dj) {
                        int t = di * 3 + dj;
                        const float* tv = t1 + ((y + di) * 28 + (xx + dj)) * 9;
                        const float* w  = ws1 + (c * 9 + t) * 8;
                        float acc2 = wb1[c * 9 + t] * tv[0];
#pragma unroll
                        for (int g = 0; g < 8; ++g) acc2 += w[g] * tv[1 + g];
                        acc += acc2;
                    }
                }
                m = fmaxf(m, acc);
            }
        }
        h1[oidx] = m;
    }
    __syncthreads();

    // ---- Phase 3: transform h1 -> t2 [169 pos][45 ch] ------------------
    for (int i = tid; i < 845; i += 256) {
        int c = i / 169, pp = i % 169;
        float v = h1[i];
        float* t = t2 + pp * 45 + c * 9;
        float bs[8];
        bspline8(v, bs);
        t[0] = silu_f(v);
#pragma unroll
        for (int g = 0; g < 8; ++g) t[1 + g] = bs[g];
    }
    __syncthreads();

    // ---- Phase 4: conv2 5x5 (45 tch -> 5) -> h2 [5,9,9] ----------------
    for (int oidx = tid; oidx < 405; oidx += 256) {
        int o  = oidx / 81;
        int pp = oidx % 81;
        int y = pp / 9, xx = pp % 9;
        float acc = 0.0f;
        for (int c = 0; c < 5; ++c) {
            for (int di = 0; di < 5; ++di) {
                for (int dj = 0; dj < 5; ++dj) {
                    int fi = c * 25 + di * 5 + dj;
                    const float* tv = t2 + ((y + di) * 13 + (xx + dj)) * 45 + c * 9;
                    const float* w  = ws2 + (o * 125 + fi) * 8;
                    float acc2 = wb2[o * 125 + fi] * tv[0];
#pragma unroll
                    for (int g = 0; g < 8; ++g) acc2 += w[g] * tv[1 + g];
                    acc += acc2;
                }
            }
        }
        h2[oidx] = acc;
    }
    __syncthreads();

    // ---- Phase 5: transform h2 -> t3 [81 pos][45 ch] -------------------
    for (int i = tid; i < 405; i += 256) {
        int c = i / 81, pp = i % 81;
        float v = h2[i];
        float* t = t3 + pp * 45 + c * 9;
        float bs[8];
        bspline8(v, bs);
        t[0] = silu_f(v);
#pragma unroll
        for (int g = 0; g < 8; ++g) t[1 + g] = bs[g];
    }
    __syncthreads();

    // ---- Phase 6: conv3 3x3 (45 tch -> 2) -> h3 [2,7,7] = [98] ---------
    for (int oidx = tid; oidx < 98; oidx += 256) {
        int o  = oidx / 49;
        int pp = oidx % 49;
        int y = pp / 7, xx = pp % 7;
        float acc = 0.0f;
        for (int c = 0; c < 5; ++c) {
            for (int di = 0; di < 3; ++di) {
                for (int dj = 0; dj < 3; ++dj) {
                    int fi = c * 9 + di * 3 + dj;
                    const float* tv = t3 + ((y + di) * 9 + (xx + dj)) * 45 + c * 9;
                    const float* w  = ws3 + (o * 45 + fi) * 8;
                    float acc2 = wb3[o * 45 + fi] * tv[0];
#pragma unroll
                    for (int g = 0; g < 8; ++g) acc2 += w[g] * tv[1 + g];
                    acc += acc2;
                }
            }
        }
        h3[oidx] = acc;
    }
    __syncthreads();

    // ---- Phase 7: FC [98] -> [200] -------------------------------------
    for (int o = tid; o < 200; o += 256) {
        float acc = fcb[o];
        const float* w = fcw + o * 98;
#pragma unroll 7
        for (int j = 0; j < 98; ++j) acc += w[j] * h3[j];
        out[b * 200 + o] = acc;
    }
}

extern "C" void kernel_launch(void* const* d_in, const int* in_sizes, int n_in,
                              void* d_out, int out_size, void* d_ws, size_t ws_size,
                              hipStream_t stream) {
    const float* x   = (const float*)d_in[0];
    const float* wb1 = (const float*)d_in[1];
    const float* ws1 = (const float*)d_in[2];
    const float* wb2 = (const float*)d_in[3];
    const float* ws2 = (const float*)d_in[4];
    const float* wb3 = (const float*)d_in[5];
    const float* ws3 = (const float*)d_in[6];
    const float* fcw = (const float*)d_in[7];
    const float* fcb = (const float*)d_in[8];
    float* out = (float*)d_out;

    int B = in_sizes[0] / 784;  // 4096
    kan_fused<<<B, 256, 0, stream>>>(x, wb1, ws1, wb2, ws2, wb3, ws3, fcw, fcb, out);
}

// Round 2
// 491.815 us; speedup vs baseline: 1.4057x; 1.4057x over previous
//
#include <hip/hip_runtime.h>

// KAN conv feature extractor, fully fused: one workgroup (256 thr) per batch element.
// conv1 3x3 (1->5) + maxpool2 -> conv2 5x5 (5->5) -> conv3 3x3 (5->2) -> FC(98->200)
// Each KAN conv = plain conv over "transformed" channels per input value v:
//   [silu(v), B0(v)..B7(v)]  stored padded to 12 floats (16B-aligned) for ds_read_b128.
// Patch feature ordering (jax conv_general_dilated_patches): F = c*k*k + di*k + dj.
// Weight indices are wave-uniform (lane = position) -> scalar s_load broadcasts.

__device__ __forceinline__ float silu_f(float v) {
    return v / (1.0f + __expf(-v));
}

// Cox-de Boor cubic B-spline basis, uniform knots grid[j] = (j-3)*0.4 - 1.
__device__ __forceinline__ void bspline8(float x, float* out) {
    const float h = 0.4f;
    float b[11];
#pragma unroll
    for (int j = 0; j < 11; ++j) {
        float gj  = (j - 3) * h - 1.0f;
        float gj1 = (j - 2) * h - 1.0f;
        b[j] = (x >= gj && x < gj1) ? 1.0f : 0.0f;
    }
#pragma unroll
    for (int p = 1; p <= 3; ++p) {
        float inv = 1.0f / (p * h);
#pragma unroll
        for (int j = 0; j + p < 11; ++j) {
            float gj   = (j - 3) * h - 1.0f;       // grid[j]
            float gjp1 = (j + p - 2) * h - 1.0f;   // grid[j+p+1]
            b[j] = (x - gj) * inv * b[j] + (gjp1 - x) * inv * b[j + 1];
        }
    }
#pragma unroll
    for (int j = 0; j < 8; ++j) out[j] = b[j];
}

// Write one transformed value (silu + 8 bases + 3 pad zeros) as 3x float4.
__device__ __forceinline__ void write_t12(float* t, float v) {
    float bs[8];
    bspline8(v, bs);
    ((float4*)t)[0] = make_float4(silu_f(v), bs[0], bs[1], bs[2]);
    ((float4*)t)[1] = make_float4(bs[3], bs[4], bs[5], bs[6]);
    ((float4*)t)[2] = make_float4(bs[7], 0.0f, 0.0f, 0.0f);
}

// LDS layout (floats), overlaid regions with barriers between phases:
//  A [0, 10140): t1 [784][12] (9408) | t2 [169][60] (10140) | t3 [81][60] (4860)
//  C [10140, 10985): h1 [5*169]=845 | h2 [5*81]=405 | h3 [98]
#define A_OFF 0
#define C_OFF 10140
#define SMEM_FLOATS 10988

__global__ __launch_bounds__(256) void kan_fused(
    const float* __restrict__ x,     // [B,1,28,28]
    const float* __restrict__ wb1,   // [5,9]
    const float* __restrict__ ws1,   // [5,9,8]
    const float* __restrict__ wb2,   // [5,125]
    const float* __restrict__ ws2,   // [5,125,8]
    const float* __restrict__ wb3,   // [2,45]
    const float* __restrict__ ws3,   // [2,45,8]
    const float* __restrict__ fcw,   // [200,98]
    const float* __restrict__ fcb,   // [200]
    float* __restrict__ out)         // [B,200]
{
    __shared__ __align__(16) float smem[SMEM_FLOATS];
    float* tA = smem + A_OFF;
    float* hC = smem + C_OFF;

    const int b   = blockIdx.x;
    const int tid = threadIdx.x;

    // ---- Phase 1: transform input pixels -> t1 [784][12] ----------------
#pragma unroll 1
    for (int i = tid; i < 784; i += 256) {
        write_t12(&tA[i * 12], x[b * 784 + i]);
    }
    __syncthreads();

    // ---- Phase 2: conv1 3x3 (9tch -> 5) fused with maxpool2 -> h1 [5][169]
    // lane = pooled position; 4x4 input-pixel window in registers,
    // reused across 4 sub-positions and 5 output channels.
#pragma unroll 1
    for (int pp = tid; pp < 169; pp += 256) {
        int ph = pp / 13, pw = pp % 13;
        float acc[2][2][5];
#pragma unroll
        for (int dy = 0; dy < 2; ++dy)
#pragma unroll
            for (int dx = 0; dx < 2; ++dx)
#pragma unroll
                for (int c = 0; c < 5; ++c) acc[dy][dx][c] = 0.0f;

#pragma unroll 1
        for (int k = 0; k < 4; ++k) {           // input row within 4x4 window
            int r = 2 * ph + k;
            float px[4][12];
#pragma unroll
            for (int p = 0; p < 4; ++p) {
                const float* src = &tA[(r * 28 + 2 * pw + p) * 12];
                float4 a0 = ((const float4*)src)[0];
                float4 a1 = ((const float4*)src)[1];
                float4 a2 = ((const float4*)src)[2];
                px[p][0] = a0.x; px[p][1] = a0.y; px[p][2]  = a0.z; px[p][3]  = a0.w;
                px[p][4] = a1.x; px[p][5] = a1.y; px[p][6]  = a1.z; px[p][7]  = a1.w;
                px[p][8] = a2.x;
            }
#pragma unroll
            for (int dy = 0; dy < 2; ++dy) {
                int di = k - dy;
                if (di < 0 || di > 2) continue; // uniform predicate
#pragma unroll
                for (int dx = 0; dx < 2; ++dx) {
#pragma unroll
                    for (int c = 0; c < 5; ++c) {
#pragma unroll
                        for (int dj = 0; dj < 3; ++dj) {
                            int t = di * 3 + dj;        // uniform
                            const float* w = &ws1[(c * 9 + t) * 8];
                            float s = wb1[c * 9 + t] * px[dx + dj][0];
#pragma unroll
                            for (int g = 0; g < 8; ++g) s += w[g] * px[dx + dj][1 + g];
                            acc[dy][dx][c] += s;
                        }
                    }
                }
            }
        }
#pragma unroll
        for (int c = 0; c < 5; ++c) {
            float m = fmaxf(fmaxf(acc[0][0][c], acc[0][1][c]),
                            fmaxf(acc[1][0][c], acc[1][1][c]));
            hC[c * 169 + pp] = m;
        }
    }
    __syncthreads();

    // ---- Phase 3: transform h1 -> t2 [169 pos][5c][12] -------------------
#pragma unroll 1
    for (int i = tid; i < 845; i += 256) {
        int c = i / 169, pp = i % 169;
        write_t12(&tA[pp * 60 + c * 12], hC[i]);
    }
    __syncthreads();

    // ---- Phase 4: conv2 5x5 (45tch -> 5) -> h2 [5][81] -------------------
    // lane = output position; row of 5 taps in registers, reused across 5 o.
#pragma unroll 1
    for (int pp = tid; pp < 81; pp += 256) {
        int y = pp / 9, xx = pp % 9;
        float acc[5] = {0.f, 0.f, 0.f, 0.f, 0.f};
#pragma unroll 1
        for (int c = 0; c < 5; ++c) {
#pragma unroll 1
            for (int di = 0; di < 5; ++di) {
                const float* base = &tA[((y + di) * 13 + xx) * 60 + c * 12];
                float row[5][9];
#pragma unroll
                for (int p = 0; p < 5; ++p) {
                    float4 a0 = ((const float4*)(base + p * 60))[0];
                    float4 a1 = ((const float4*)(base + p * 60))[1];
                    float  a2 = base[p * 60 + 8];
                    row[p][0] = a0.x; row[p][1] = a0.y; row[p][2] = a0.z; row[p][3] = a0.w;
                    row[p][4] = a1.x; row[p][5] = a1.y; row[p][6] = a1.z; row[p][7] = a1.w;
                    row[p][8] = a2;
                }
#pragma unroll
                for (int o = 0; o < 5; ++o) {
#pragma unroll
                    for (int dj = 0; dj < 5; ++dj) {
                        int fi = c * 25 + di * 5 + dj;   // uniform
                        const float* w = &ws2[(o * 125 + fi) * 8];
                        float s = wb2[o * 125 + fi] * row[dj][0];
#pragma unroll
                        for (int g = 0; g < 8; ++g) s += w[g] * row[dj][1 + g];
                        acc[o] += s;
                    }
                }
            }
        }
#pragma unroll
        for (int o = 0; o < 5; ++o) hC[o * 81 + pp] = acc[o];
    }
    __syncthreads();

    // ---- Phase 5: transform h2 -> t3 [81 pos][5c][12] --------------------
#pragma unroll 1
    for (int i = tid; i < 405; i += 256) {
        int c = i / 81, pp = i % 81;
        write_t12(&tA[pp * 60 + c * 12], hC[i]);
    }
    __syncthreads();

    // ---- Phase 6: conv3 3x3 (45tch -> 2) -> h3 [98] ----------------------
    float h3v[2];  // also keep in regs for the write
#pragma unroll 1
    for (int pp = tid; pp < 49; pp += 256) {
        int y = pp / 7, xx = pp % 7;
        float acc[2] = {0.f, 0.f};
#pragma unroll 1
        for (int c = 0; c < 5; ++c) {
#pragma unroll 1
            for (int di = 0; di < 3; ++di) {
                const float* base = &tA[((y + di) * 9 + xx) * 60 + c * 12];
                float row[3][9];
#pragma unroll
                for (int p = 0; p < 3; ++p) {
                    float4 a0 = ((const float4*)(base + p * 60))[0];
                    float4 a1 = ((const float4*)(base + p * 60))[1];
                    float  a2 = base[p * 60 + 8];
                    row[p][0] = a0.x; row[p][1] = a0.y; row[p][2] = a0.z; row[p][3] = a0.w;
                    row[p][4] = a1.x; row[p][5] = a1.y; row[p][6] = a1.z; row[p][7] = a1.w;
                    row[p][8] = a2;
                }
#pragma unroll
                for (int o = 0; o < 2; ++o) {
#pragma unroll
                    for (int dj = 0; dj < 3; ++dj) {
                        int fi = c * 9 + di * 3 + dj;    // uniform
                        const float* w = &ws3[(o * 45 + fi) * 8];
                        float s = wb3[o * 45 + fi] * row[dj][0];
#pragma unroll
                        for (int g = 0; g < 8; ++g) s += w[g] * row[dj][1 + g];
                        acc[o] += s;
                    }
                }
            }
        }
        h3v[0] = acc[0]; h3v[1] = acc[1];
        hC[0 * 49 + pp] = acc[0];
        hC[1 * 49 + pp] = acc[1];
    }
    (void)h3v;
    __syncthreads();

    // ---- Phase 7: FC [98] -> [200] ---------------------------------------
#pragma unroll 1
    for (int o = tid; o < 200; o += 256) {
        float acc = fcb[o];
        const float* w = fcw + o * 98;   // o*98 even -> 8B-aligned float2 loads
#pragma unroll
        for (int j = 0; j < 98; j += 2) {
            float2 wv = *(const float2*)(w + j);
            acc += wv.x * hC[j] + wv.y * hC[j + 1];  // hC reads are same-address broadcasts
        }
        out[b * 200 + o] = acc;
    }
}

extern "C" void kernel_launch(void* const* d_in, const int* in_sizes, int n_in,
                              void* d_out, int out_size, void* d_ws, size_t ws_size,
                              hipStream_t stream) {
    const float* x   = (const float*)d_in[0];
    const float* wb1 = (const float*)d_in[1];
    const float* ws1 = (const float*)d_in[2];
    const float* wb2 = (const float*)d_in[3];
    const float* ws2 = (const float*)d_in[4];
    const float* wb3 = (const float*)d_in[5];
    const float* ws3 = (const float*)d_in[6];
    const float* fcw = (const float*)d_in[7];
    const float* fcb = (const float*)d_in[8];
    float* out = (float*)d_out;

    int B = in_sizes[0] / 784;  // 4096
    kan_fused<<<B, 256, 0, stream>>>(x, wb1, ws1, wb2, ws2, wb3, ws3, fcw, fcb, out);
}

// Round 3
// 248.745 us; speedup vs baseline: 2.7794x; 1.9772x over previous
//
#include <hip/hip_runtime.h>

// KAN conv feature extractor, fully fused: one workgroup (256 thr) per batch element.
// conv1 3x3 (1->5) + maxpool2 -> conv2 5x5 (5->5) -> conv3 3x3 (5->2) -> FC(98->200)
// Activations stored in LDS as fp16 "records" of 12 halves (24B, 8B-aligned,
// conflict-free lane strides): [silu, B0..B7, 0, pad, pad].
// Inner products via v_dot2_f32_f16 (fp32 accumulate). Weights pre-packed to fp16
// 10-half records in d_ws by a prep kernel; weight indices are wave-uniform -> s_load.

typedef _Float16 h2 __attribute__((ext_vector_type(2)));
typedef unsigned int uint_t;

__device__ __forceinline__ h2 as_h2(uint_t u) { union { uint_t u; h2 h; } c; c.u = u; return c.h; }
__device__ __forceinline__ uint_t pk(float a, float b) {
    h2 v; v[0] = (_Float16)a; v[1] = (_Float16)b;
    union { h2 h; uint_t u; } c; c.h = v; return c.u;
}

__device__ __forceinline__ float fdot2f(h2 a, h2 b, float c) {
#if __has_builtin(__builtin_amdgcn_fdot2)
    return __builtin_amdgcn_fdot2(a, b, c, false);
#else
    return c + (float)a[0] * (float)b[0] + (float)a[1] * (float)b[1];
#endif
}

__device__ __forceinline__ float silu_f(float v) {
    return v / (1.0f + __expf(-v));
}

// Cox-de Boor cubic B-spline basis, uniform knots grid[j] = (j-3)*0.4 - 1.
__device__ __forceinline__ void bspline8(float x, float* out) {
    const float h = 0.4f;
    float b[11];
#pragma unroll
    for (int j = 0; j < 11; ++j) {
        float gj  = (j - 3) * h - 1.0f;
        float gj1 = (j - 2) * h - 1.0f;
        b[j] = (x >= gj && x < gj1) ? 1.0f : 0.0f;
    }
#pragma unroll
    for (int p = 1; p <= 3; ++p) {
        float inv = 1.0f / (p * h);
#pragma unroll
        for (int j = 0; j + p < 11; ++j) {
            float gj   = (j - 3) * h - 1.0f;       // grid[j]
            float gjp1 = (j + p - 2) * h - 1.0f;   // grid[j+p+1]
            b[j] = (x - gj) * inv * b[j] + (gjp1 - x) * inv * b[j + 1];
        }
    }
#pragma unroll
    for (int j = 0; j < 8; ++j) out[j] = b[j];
}

// Transform value v -> fp16 record [silu, B0..B7, 0] at p (halves, 8B-aligned).
__device__ __forceinline__ void write_rec(_Float16* p, float v) {
    float bs[8];
    bspline8(v, bs);
    float s = silu_f(v);
    uint2 w0, w1;
    w0.x = pk(s, bs[0]);     w0.y = pk(bs[1], bs[2]);
    w1.x = pk(bs[3], bs[4]); w1.y = pk(bs[5], bs[6]);
    *(uint2*)(p)     = w0;
    *(uint2*)(p + 4) = w1;
    *(uint_t*)(p + 8) = pk(bs[7], 0.0f);   // explicit 0 pad: no NaN garbage in dot2
}

struct Rec { h2 a[5]; };
__device__ __forceinline__ Rec load_rec(const _Float16* p) {
    uint2  u0 = *(const uint2*)(p);
    uint2  u1 = *(const uint2*)(p + 4);
    uint_t u2 = *(const uint_t*)(p + 8);
    Rec r;
    r.a[0] = as_h2(u0.x); r.a[1] = as_h2(u0.y);
    r.a[2] = as_h2(u1.x); r.a[3] = as_h2(u1.y);
    r.a[4] = as_h2(u2);
    return r;
}

// d_ws layout: [0)      w16: fp16 weight records, 10 halves each:
//                        W1: rec (c*9+t), 45 recs   @ half 0
//                        W2: rec (o*125+c*25+di*5+dj), 625 recs @ half 450
//                        W3: rec (o*45+c*9+di*3+dj), 90 recs    @ half 6700
//              [15360)  fcwT: float [98][200] (transposed FC weights)
#define W2_OFF 450
#define W3_OFF 6700
#define FCWT_BYTE_OFF 15360

__global__ __launch_bounds__(256) void kan_prep(
    const float* __restrict__ wb1, const float* __restrict__ ws1,
    const float* __restrict__ wb2, const float* __restrict__ ws2,
    const float* __restrict__ wb3, const float* __restrict__ ws3,
    const float* __restrict__ fcw, _Float16* __restrict__ w16,
    float* __restrict__ fcwT)
{
    int gtid = blockIdx.x * 256 + threadIdx.x;
    int gstr = gridDim.x * 256;
    for (int i = gtid; i < 760; i += gstr) {
        const float *wb, *ws; int r;
        if (i < 45)       { wb = wb1; ws = ws1; r = i; }
        else if (i < 670) { wb = wb2; ws = ws2; r = i - 45; }
        else              { wb = wb3; ws = ws3; r = i - 670; }
        _Float16* p = w16 + i * 10;
        p[0] = (_Float16)wb[r];
#pragma unroll
        for (int g = 0; g < 8; ++g) p[1 + g] = (_Float16)ws[r * 8 + g];
        p[9] = (_Float16)0.0f;
    }
    for (int i = gtid; i < 19600; i += gstr) {
        int o = i / 98, j = i % 98;
        fcwT[j * 200 + o] = fcw[i];
    }
}

// LDS: smemA (fp16 records, overlaid): t1 [784][12]=9408h | t2 [169 pos][5c][12]=10140h
//      | t3 [81 pos][5o][12]=4860h.  smemB (overlaid): P2h fp16 [5][676]=3380h |
//      h2buf f32 [405] | h3 f32 [98].  Total 27 KB -> 5 WG/CU.
__global__ __launch_bounds__(256) void kan_fused(
    const float* __restrict__ x,      // [B,1,28,28]
    const _Float16* __restrict__ w16, // packed weights (d_ws)
    const float* __restrict__ fcwT,   // [98][200]
    const float* __restrict__ fcb,    // [200]
    float* __restrict__ out)          // [B,200]
{
    __shared__ __align__(16) _Float16 smemA[10140];
    __shared__ __align__(16) float    smemB[1690];
    _Float16* P2h   = (_Float16*)smemB;  // [c][676]
    float*    h2buf = smemB;             // [o*81+pp]
    float*    h3f   = smemB;             // [98]

    const int b   = blockIdx.x;
    const int tid = threadIdx.x;

    // ---- Phase 1: transform input pixels -> t1 records -------------------
#pragma unroll 1
    for (int i = tid; i < 784; i += 256)
        write_rec(&smemA[i * 12], x[b * 784 + i]);
    __syncthreads();

    // ---- Phase 2: conv1 3x3 at every sub-position (26x26), 5 out ch ------
    // lane = sub-position: stride-12 record reads, conflict-free; weights uniform.
#pragma unroll 1
    for (int s = tid; s < 676; s += 256) {
        int y = s / 26, xx = s % 26;
        Rec r[9];
#pragma unroll
        for (int t = 0; t < 9; ++t)
            r[t] = load_rec(&smemA[((y + t / 3) * 28 + xx + t % 3) * 12]);
        float acc[5] = {0.f, 0.f, 0.f, 0.f, 0.f};
#pragma unroll
        for (int t = 0; t < 9; ++t) {
#pragma unroll
            for (int c = 0; c < 5; ++c) {
                const h2* w = (const h2*)(w16 + (c * 9 + t) * 10);
                float a = acc[c];
#pragma unroll
                for (int q = 0; q < 5; ++q) a = fdot2f(r[t].a[q], w[q], a);
                acc[c] = a;
            }
        }
#pragma unroll
        for (int c = 0; c < 5; ++c) P2h[c * 676 + s] = (_Float16)acc[c];
    }
    __syncthreads();

    // ---- Phase 3: maxpool2 + transform -> t2 records ---------------------
#pragma unroll 1
    for (int i = tid; i < 845; i += 256) {
        int c = i / 169, pp = i % 169;
        int ph = pp / 13, pw = pp % 13;
        const _Float16* q = P2h + c * 676 + (2 * ph) * 26 + 2 * pw;
        h2 a = as_h2(*(const uint_t*)q);
        h2 d = as_h2(*(const uint_t*)(q + 26));
        float m = fmaxf(fmaxf((float)a[0], (float)a[1]),
                        fmaxf((float)d[0], (float)d[1]));
        write_rec(&smemA[pp * 60 + c * 12], m);
    }
    __syncthreads();

    // ---- Phase 4: conv2 5x5 (5c x 9feat -> 5o) -> h2buf ------------------
    if (tid < 81) {
        int y = tid / 9, xx = tid % 9;
        float acc[5] = {0.f, 0.f, 0.f, 0.f, 0.f};
#pragma unroll 1
        for (int c = 0; c < 5; ++c) {
#pragma unroll 1
            for (int di = 0; di < 5; ++di) {
                const _Float16* base = &smemA[((y + di) * 13 + xx) * 60 + c * 12];
                Rec r[5];
#pragma unroll
                for (int p = 0; p < 5; ++p) r[p] = load_rec(base + p * 60);
#pragma unroll
                for (int o = 0; o < 5; ++o) {
                    const h2* w = (const h2*)(w16 + (W2_OFF + (o * 125 + c * 25 + di * 5) * 10));
                    float a = acc[o];
#pragma unroll
                    for (int dj = 0; dj < 5; ++dj)
#pragma unroll
                        for (int q = 0; q < 5; ++q)
                            a = fdot2f(r[dj].a[q], w[dj * 5 + q], a);
                    acc[o] = a;
                }
            }
        }
#pragma unroll
        for (int o = 0; o < 5; ++o) h2buf[o * 81 + tid] = acc[o];
    }
    __syncthreads();

    // ---- Phase 5: transform h2 -> t3 records -----------------------------
#pragma unroll 1
    for (int i = tid; i < 405; i += 256) {
        int o = i / 81, pp = i % 81;
        write_rec(&smemA[pp * 60 + o * 12], h2buf[i]);
    }
    __syncthreads();

    // ---- Phase 6: conv3 3x3 (5c x 9feat -> 2o) -> h3 ---------------------
    if (tid < 49) {
        int y = tid / 7, xx = tid % 7;
        float acc[2] = {0.f, 0.f};
#pragma unroll 1
        for (int c = 0; c < 5; ++c) {
#pragma unroll 1
            for (int di = 0; di < 3; ++di) {
                const _Float16* base = &smemA[((y + di) * 9 + xx) * 60 + c * 12];
                Rec r[3];
#pragma unroll
                for (int p = 0; p < 3; ++p) r[p] = load_rec(base + p * 60);
#pragma unroll
                for (int o = 0; o < 2; ++o) {
                    const h2* w = (const h2*)(w16 + (W3_OFF + (o * 45 + c * 9 + di * 3) * 10));
                    float a = acc[o];
#pragma unroll
                    for (int dj = 0; dj < 3; ++dj)
#pragma unroll
                        for (int q = 0; q < 5; ++q)
                            a = fdot2f(r[dj].a[q], w[dj * 5 + q], a);
                    acc[o] = a;
                }
            }
        }
        h3f[0 * 49 + tid] = acc[0];
        h3f[1 * 49 + tid] = acc[1];
    }
    __syncthreads();

    // ---- Phase 7: FC [98] -> [200] (coalesced transposed weights) --------
    if (tid < 200) {
        float acc = fcb[tid];
#pragma unroll 7
        for (int j = 0; j < 98; ++j)
            acc += fcwT[j * 200 + tid] * h3f[j];   // h3f: same-address broadcast
        out[b * 200 + tid] = acc;
    }
}

extern "C" void kernel_launch(void* const* d_in, const int* in_sizes, int n_in,
                              void* d_out, int out_size, void* d_ws, size_t ws_size,
                              hipStream_t stream) {
    const float* x   = (const float*)d_in[0];
    const float* wb1 = (const float*)d_in[1];
    const float* ws1 = (const float*)d_in[2];
    const float* wb2 = (const float*)d_in[3];
    const float* ws2 = (const float*)d_in[4];
    const float* wb3 = (const float*)d_in[5];
    const float* ws3 = (const float*)d_in[6];
    const float* fcw = (const float*)d_in[7];
    const float* fcb = (const float*)d_in[8];
    float* out = (float*)d_out;

    _Float16* w16  = (_Float16*)d_ws;
    float*    fcwT = (float*)((char*)d_ws + FCWT_BYTE_OFF);

    kan_prep<<<32, 256, 0, stream>>>(wb1, ws1, wb2, ws2, wb3, ws3, fcw, w16, fcwT);

    int B = in_sizes[0] / 784;  // 4096
    kan_fused<<<B, 256, 0, stream>>>(x, w16, fcwT, fcb, out);
}